// Round 1
// baseline (865.004 us; speedup 1.0000x reference)
//
#include <hip/hip_runtime.h>
#include <math.h>

// Problem constants (all compile-time from the reference)
#define NB      32      // NUM_BLOCKS = D_HEAD/3
#define NHEADS  8
#define DH      96
#define DT      64
#define HALFT   32
#define BB      2
#define TT      8
#define HH      64
#define WW      64

typedef float f32x4 __attribute__((ext_vector_type(4)));
typedef float f32x2 __attribute__((ext_vector_type(2)));

// ---------------------------------------------------------------------------
// Kernel 1: temporal embedding  temp[b*T+t][d] = emb @ Wt.T + bt
//   emb interleaved: [cos(p*f0), sin(p*f0), cos(p*f1), ...]
// grid = B*T (16), block = 96. Trivial cost; use precise sincosf.
// ---------------------------------------------------------------------------
__global__ void temp_kernel(const float* __restrict__ time_pos,
                            const float* __restrict__ freq_temporal,
                            const float* __restrict__ Wt,
                            const float* __restrict__ bt,
                            float* __restrict__ temp) {
    const int row = blockIdx.x;       // 0..15  (b*T + t)
    const int d   = threadIdx.x;      // 0..95
    const float p = time_pos[row];
    const float* __restrict__ wrow = Wt + d * DT;
    float sum = bt[d];
    #pragma unroll
    for (int j = 0; j < HALFT; ++j) {
        float s, c;
        sincosf(p * freq_temporal[j], &s, &c);
        sum = fmaf(c, wrow[2 * j], sum);
        sum = fmaf(s, wrow[2 * j + 1], sum);
    }
    temp[row * DH + d] = sum;
}

// ---------------------------------------------------------------------------
// Kernel 2: spatio rotation + temporal add.
// v2: one thread per FOUR 3-elem blocks (12 floats = 3x dwordx4 per tensor).
//   - every global access is an aligned 16B dwordx4 (48B*g offsets)
//   - index decode + spatial_pos/freq/temp lookups amortized 4x
//   - nontemporal hints on the 4 streaming tensors (805 MB, zero reuse)
// Group index g over (b, t, head, y, x, blk4), all pow2 dims:
//   blk4 = g & 7 (blk = 4*blk4 + r), x = (g>>3)&63, y = (g>>9)&63,
//   head = (g>>15)&7, t = (g>>18)&7, b = g>>21.   float offset = 12*g.
// ---------------------------------------------------------------------------
__global__ __launch_bounds__(256) void rope_kernel(
        const float* __restrict__ q,
        const float* __restrict__ k,
        const float* __restrict__ spatial_pos,
        const float* __restrict__ freq_spatial,
        const float* __restrict__ temp,
        float* __restrict__ qo,
        float* __restrict__ ko) {
    const unsigned g = blockIdx.x * 256u + threadIdx.x;   // 0 .. 2^22-1

    const int b4   = g & 7;
    const int x    = (g >> 3)  & 63;
    const int y    = (g >> 9)  & 63;
    const int head = (g >> 15) & 7;
    const int t    = (g >> 18) & 7;
    const int b    = (int)(g >> 21);

    // broadcast tables (L1/L2 resident; ~2 distinct addrs per wave for spatial)
    const int sp = ((b * HH + y) * WW + x) * 2;
    const f32x2 ll = *(const f32x2*)(spatial_pos + sp);
    const float lat = ll[0], lon = ll[1];

    // freqs for 4 consecutive blocks: 8 floats, 32B-aligned
    const f32x4* __restrict__ fptr =
        (const f32x4*)(freq_spatial + (head * NB + b4 * 4) * 2);
    const f32x4 f01 = fptr[0];    // fa0 fb0 fa1 fb1
    const f32x4 f23 = fptr[1];    // fa2 fb2 fa3 fb3
    const float fa[4] = { f01[0], f01[2], f23[0], f23[2] };
    const float fb[4] = { f01[1], f01[3], f23[1], f23[3] };

    // temp chunk for these 12 channels: 3x dwordx4 (48B-aligned offset)
    const float* __restrict__ trow = temp + (b * TT + t) * DH + b4 * 12;
    float tv[12];
    {
        const f32x4 t0 = ((const f32x4*)trow)[0];
        const f32x4 t1 = ((const f32x4*)trow)[1];
        const f32x4 t2 = ((const f32x4*)trow)[2];
        #pragma unroll
        for (int c = 0; c < 4; ++c) {
            tv[c] = t0[c]; tv[4 + c] = t1[c]; tv[8 + c] = t2[c];
        }
    }

    // streaming loads: 12 floats each of q, k as 3x dwordx4, nontemporal
    const size_t e = (size_t)g * 12u;
    float qf[12], kf[12];
    {
        const f32x4* __restrict__ qp = (const f32x4*)(q + e);
        const f32x4* __restrict__ kp = (const f32x4*)(k + e);
        #pragma unroll
        for (int v = 0; v < 3; ++v) {
            const f32x4 qv = __builtin_nontemporal_load(qp + v);
            const f32x4 kv = __builtin_nontemporal_load(kp + v);
            #pragma unroll
            for (int c = 0; c < 4; ++c) {
                qf[4 * v + c] = qv[c];
                kf[4 * v + c] = kv[c];
            }
        }
    }

    // rotate 4 blocks; angles tiny (|A| < ~0.2) so fast-path sincos is fine
    // o0 =  x0*cA + x1*sA
    // o1 =  cB*u + x2*sB      where u = x1*cA - x0*sA
    // o2 = -sB*u + x2*cB
    float qr[12], kr[12];
    #pragma unroll
    for (int r = 0; r < 4; ++r) {
        float sA, cA, sB, cB;
        __sincosf(lon * fa[r], &sA, &cA);
        __sincosf(lat * fb[r], &sB, &cB);

        const float q0 = qf[3 * r], q1 = qf[3 * r + 1], q2 = qf[3 * r + 2];
        const float k0 = kf[3 * r], k1 = kf[3 * r + 1], k2 = kf[3 * r + 2];

        const float uq = q1 * cA - q0 * sA;
        qr[3 * r]     = q0 * cA + q1 * sA + tv[3 * r];
        qr[3 * r + 1] = cB * uq + q2 * sB + tv[3 * r + 1];
        qr[3 * r + 2] = -sB * uq + q2 * cB + tv[3 * r + 2];

        const float uk = k1 * cA - k0 * sA;
        kr[3 * r]     = k0 * cA + k1 * sA + tv[3 * r];
        kr[3 * r + 1] = cB * uk + k2 * sB + tv[3 * r + 1];
        kr[3 * r + 2] = -sB * uk + k2 * cB + tv[3 * r + 2];
    }

    // streaming stores: 3x dwordx4 per tensor, nontemporal (no reuse)
    {
        f32x4* __restrict__ qop = (f32x4*)(qo + e);
        f32x4* __restrict__ kop = (f32x4*)(ko + e);
        #pragma unroll
        for (int v = 0; v < 3; ++v) {
            f32x4 qv, kv;
            #pragma unroll
            for (int c = 0; c < 4; ++c) {
                qv[c] = qr[4 * v + c];
                kv[c] = kr[4 * v + c];
            }
            __builtin_nontemporal_store(qv, qop + v);
            __builtin_nontemporal_store(kv, kop + v);
        }
    }
}

// ---------------------------------------------------------------------------
extern "C" void kernel_launch(void* const* d_in, const int* in_sizes, int n_in,
                              void* d_out, int out_size, void* d_ws, size_t ws_size,
                              hipStream_t stream) {
    const float* q             = (const float*)d_in[0];
    const float* k             = (const float*)d_in[1];
    const float* spatial_pos   = (const float*)d_in[2];
    const float* time_pos      = (const float*)d_in[3];
    const float* freq_spatial  = (const float*)d_in[4];
    const float* freq_temporal = (const float*)d_in[5];
    const float* Wt            = (const float*)d_in[6];
    const float* bt            = (const float*)d_in[7];

    float* out  = (float*)d_out;
    float* temp = (float*)d_ws;                       // 16*96*4 = 6144 B

    temp_kernel<<<BB * TT, DH, 0, stream>>>(time_pos, freq_temporal, Wt, bt, temp);

    const unsigned n_groups = BB * TT * NHEADS * HH * WW * (NB / 4);  // 2^22
    const size_t per_tensor = (size_t)n_groups * 12u;                 // 50,331,648
    rope_kernel<<<n_groups / 256, 256, 0, stream>>>(
        q, k, spatial_pos, freq_spatial, temp, out, out + per_tensor);
}

// Round 2
// 661.812 us; speedup vs baseline: 1.3070x; 1.3070x over previous
//
#include <hip/hip_runtime.h>
#include <math.h>

// Problem constants (all compile-time from the reference)
#define NB      32      // NUM_BLOCKS = D_HEAD/3
#define NHEADS  8
#define DH      96
#define DT      64
#define HALFT   32
#define BB      2
#define TT      8
#define HH      64
#define WW      64

typedef float f32x4 __attribute__((ext_vector_type(4)));
typedef float f32x2 __attribute__((ext_vector_type(2)));

// ---------------------------------------------------------------------------
// Kernel 1: temporal embedding  temp[b*T+t][d] = emb @ Wt.T + bt
//   emb interleaved: [cos(p*f0), sin(p*f0), cos(p*f1), ...]
// grid = B*T (16), block = 96. Trivial cost; use precise sincosf.
// ---------------------------------------------------------------------------
__global__ void temp_kernel(const float* __restrict__ time_pos,
                            const float* __restrict__ freq_temporal,
                            const float* __restrict__ Wt,
                            const float* __restrict__ bt,
                            float* __restrict__ temp) {
    const int row = blockIdx.x;       // 0..15  (b*T + t)
    const int d   = threadIdx.x;      // 0..95
    const float p = time_pos[row];
    const float* __restrict__ wrow = Wt + d * DT;
    float sum = bt[d];
    #pragma unroll
    for (int j = 0; j < HALFT; ++j) {
        float s, c;
        sincosf(p * freq_temporal[j], &s, &c);
        sum = fmaf(c, wrow[2 * j], sum);
        sum = fmaf(s, wrow[2 * j + 1], sum);
    }
    temp[row * DH + d] = sum;
}

// ---------------------------------------------------------------------------
// Kernel 2: spatio rotation + temporal add.
// v3: one thread per FOUR 3-elem blocks (12 floats = 3x dwordx4 per tensor),
//     PLAIN loads/stores (v2 lesson: nontemporal stores + stride-48 partial
//     16B chunks per instruction => L2 streams partial lines => HBM RMW,
//     WRITE_SIZE 1.92x ideal. Write-back L2 merges them; a wave's 3KB
//     footprint cannot be evicted between back-to-back sibling stores).
// Group index g over (b, t, head, y, x, blk4), all pow2 dims:
//   blk4 = g & 7 (blk = 4*blk4 + r), x = (g>>3)&63, y = (g>>9)&63,
//   head = (g>>15)&7, t = (g>>18)&7, b = g>>21.   float offset = 12*g.
// ---------------------------------------------------------------------------
__global__ __launch_bounds__(256) void rope_kernel(
        const float* __restrict__ q,
        const float* __restrict__ k,
        const float* __restrict__ spatial_pos,
        const float* __restrict__ freq_spatial,
        const float* __restrict__ temp,
        float* __restrict__ qo,
        float* __restrict__ ko) {
    const unsigned g = blockIdx.x * 256u + threadIdx.x;   // 0 .. 2^22-1

    const int b4   = g & 7;
    const int x    = (g >> 3)  & 63;
    const int y    = (g >> 9)  & 63;
    const int head = (g >> 15) & 7;
    const int t    = (g >> 18) & 7;
    const int b    = (int)(g >> 21);

    // broadcast tables (L1/L2 resident; ~2 distinct addrs per wave for spatial)
    const int sp = ((b * HH + y) * WW + x) * 2;
    const f32x2 ll = *(const f32x2*)(spatial_pos + sp);
    const float lat = ll[0], lon = ll[1];

    // freqs for 4 consecutive blocks: 8 floats, 32B-aligned
    const f32x4* __restrict__ fptr =
        (const f32x4*)(freq_spatial + (head * NB + b4 * 4) * 2);
    const f32x4 f01 = fptr[0];    // fa0 fb0 fa1 fb1
    const f32x4 f23 = fptr[1];    // fa2 fb2 fa3 fb3
    const float fa[4] = { f01[0], f01[2], f23[0], f23[2] };
    const float fb[4] = { f01[1], f01[3], f23[1], f23[3] };

    // temp chunk for these 12 channels: 3x dwordx4 (48B-aligned offset)
    const float* __restrict__ trow = temp + (b * TT + t) * DH + b4 * 12;
    float tv[12];
    {
        const f32x4 t0 = ((const f32x4*)trow)[0];
        const f32x4 t1 = ((const f32x4*)trow)[1];
        const f32x4 t2 = ((const f32x4*)trow)[2];
        #pragma unroll
        for (int c = 0; c < 4; ++c) {
            tv[c] = t0[c]; tv[4 + c] = t1[c]; tv[8 + c] = t2[c];
        }
    }

    // streaming loads: 12 floats each of q, k as 3x dwordx4 (plain — let
    // L2/L3 serve the sibling partial-line requests and any resident lines)
    const size_t e = (size_t)g * 12u;
    float qf[12], kf[12];
    {
        const f32x4* __restrict__ qp = (const f32x4*)(q + e);
        const f32x4* __restrict__ kp = (const f32x4*)(k + e);
        #pragma unroll
        for (int v = 0; v < 3; ++v) {
            const f32x4 qv = qp[v];
            const f32x4 kv = kp[v];
            #pragma unroll
            for (int c = 0; c < 4; ++c) {
                qf[4 * v + c] = qv[c];
                kf[4 * v + c] = kv[c];
            }
        }
    }

    // rotate 4 blocks; angles tiny (|A| < ~0.2) so fast-path sincos is fine
    // o0 =  x0*cA + x1*sA
    // o1 =  cB*u + x2*sB      where u = x1*cA - x0*sA
    // o2 = -sB*u + x2*cB
    float qr[12], kr[12];
    #pragma unroll
    for (int r = 0; r < 4; ++r) {
        float sA, cA, sB, cB;
        __sincosf(lon * fa[r], &sA, &cA);
        __sincosf(lat * fb[r], &sB, &cB);

        const float q0 = qf[3 * r], q1 = qf[3 * r + 1], q2 = qf[3 * r + 2];
        const float k0 = kf[3 * r], k1 = kf[3 * r + 1], k2 = kf[3 * r + 2];

        const float uq = q1 * cA - q0 * sA;
        qr[3 * r]     = q0 * cA + q1 * sA + tv[3 * r];
        qr[3 * r + 1] = cB * uq + q2 * sB + tv[3 * r + 1];
        qr[3 * r + 2] = -sB * uq + q2 * cB + tv[3 * r + 2];

        const float uk = k1 * cA - k0 * sA;
        kr[3 * r]     = k0 * cA + k1 * sA + tv[3 * r];
        kr[3 * r + 1] = cB * uk + k2 * sB + tv[3 * r + 1];
        kr[3 * r + 2] = -sB * uk + k2 * cB + tv[3 * r + 2];
    }

    // stores: 3x dwordx4 per tensor, PLAIN (write-back L2 merges the
    // stride-48 partial lines from sibling stores before HBM writeback)
    {
        f32x4* __restrict__ qop = (f32x4*)(qo + e);
        f32x4* __restrict__ kop = (f32x4*)(ko + e);
        #pragma unroll
        for (int v = 0; v < 3; ++v) {
            f32x4 qv, kv;
            #pragma unroll
            for (int c = 0; c < 4; ++c) {
                qv[c] = qr[4 * v + c];
                kv[c] = kr[4 * v + c];
            }
            qop[v] = qv;
            kop[v] = kv;
        }
    }
}

// ---------------------------------------------------------------------------
extern "C" void kernel_launch(void* const* d_in, const int* in_sizes, int n_in,
                              void* d_out, int out_size, void* d_ws, size_t ws_size,
                              hipStream_t stream) {
    const float* q             = (const float*)d_in[0];
    const float* k             = (const float*)d_in[1];
    const float* spatial_pos   = (const float*)d_in[2];
    const float* time_pos      = (const float*)d_in[3];
    const float* freq_spatial  = (const float*)d_in[4];
    const float* freq_temporal = (const float*)d_in[5];
    const float* Wt            = (const float*)d_in[6];
    const float* bt            = (const float*)d_in[7];

    float* out  = (float*)d_out;
    float* temp = (float*)d_ws;                       // 16*96*4 = 6144 B

    temp_kernel<<<BB * TT, DH, 0, stream>>>(time_pos, freq_temporal, Wt, bt, temp);

    const unsigned n_groups = BB * TT * NHEADS * HH * WW * (NB / 4);  // 2^22
    const size_t per_tensor = (size_t)n_groups * 12u;                 // 50,331,648
    rope_kernel<<<n_groups / 256, 256, 0, stream>>>(
        q, k, spatial_pos, freq_spatial, temp, out, out + per_tensor);
}